// Round 10
// baseline (112.971 us; speedup 1.0000x reference)
//
#include <hip/hip_runtime.h>

// ---------------------------------------------------------------------------
// Per-batch dynamic conv stack + polynomial attention (f32).
//   feature (8,360) = mean(thumb,(2,3)) @ Wm + bm
//   conv_stack: residual + [3x conv3x3(SAME,leaky 0.2)] -> [5x conv1x1(leaky)]
//   attention:  out = y * (1 + prod_i(a*h + b*w + c*y + d)) per channel
// Outputs: x_out (8,3,512,512) then thumb_out (8,3,64,64), flat f32.
//
// R17 = R16 math (pk-f32, dy-overlap loads, col-major LDS) on 32x64 tiles,
// 512-thread blocks, single IN-PLACE buffer:
//   * Standing finding: both pipes ~40%, occupancy ~2.4 waves/SIMD -> the
//     stall is latency with thin wave cover. 8 waves/block + 34.2KB LDS
//     raises the residency ceiling to 32 waves/CU (R16: 16).
//   * Taller tile cuts halo work: stage 38/32=1.19 (was 1.375), conv1
//     1.125 (was 1.25), conv2 1.06 (was 1.125) -> ~8% less real work.
//   * In-place buffer (R13-proven): reads->barrier->writes per layer,
//     acc in regs across the barrier. 5 barriers per 32 rows ~= R16's
//     3 per 16. Buffer row = img row + 3 throughout.
//   * CSTR=39: col step 156 = 28 mod 32 banks, period 8 -> 2 lanes/bank
//     (same engineered-free geometry as CSTR=23).
//   * (512,4): k = 4*4/8 = 2 blocks/CU target, VGPR cap 128 (we use ~48-80).
// ---------------------------------------------------------------------------

typedef float v2f __attribute__((ext_vector_type(2)));
#define FMA2(a, b, c) __builtin_elementwise_fma((a), (b), (c))

__device__ __forceinline__ v2f leaky2(v2f v) {
    return __builtin_elementwise_max(v, v * 0.2f);
}

// align-4 LDS pair load/store: compiles to ds_read2_b32 / ds_write2_b32
__device__ __forceinline__ v2f ldpair(const float* p) {
    v2f r; __builtin_memcpy(&r, p, 8); return r;
}
__device__ __forceinline__ void stpair(float* p, v2f v) {
    __builtin_memcpy(p, &v, 8);
}

constexpr int NCOLS = 73;           // cols -4..67 + zero pad col 72
constexpr int ROWS0 = 38;           // img rows trow-3 .. trow+34
constexpr int CSTR  = 39;           // 38 rows + 1 pad; 4*39=156=28 mod 32
constexpr int CHS   = NCOLS * CSTR; // 2847
constexpr int BUFSZ = 3 * CHS + 4;  // 34.2KB

__global__ __launch_bounds__(384) void prep_kernel(
    const float* __restrict__ thumb, const float* __restrict__ Wm,
    const float* __restrict__ bm, float* __restrict__ feat)
{
    const int b = blockIdx.x;                // 8 blocks
    const int t = threadIdx.x;               // 384
    const int ch = t >> 7;                   // 0..2
    const int l  = t & 127;
    const float4* p = (const float4*)(thumb + (size_t)b * 3 * 4096);
    float s = 0.f;
#pragma unroll
    for (int k = 0; k < 8; ++k) {
        float4 v = p[ch * 1024 + l + k * 128];
        s += v.x + v.y + v.z + v.w;
    }
    __shared__ float red[384];
    red[t] = s;
    __syncthreads();
    for (int off = 64; off > 0; off >>= 1) {
        if (l < off) red[t] += red[t + off];
        __syncthreads();
    }
    if (t < 360) {
        const float sc = 1.f / 4096.f;
        const float m0 = red[0] * sc, m1 = red[128] * sc, m2 = red[256] * sc;
        feat[b * 360 + t] =
            fmaf(m0, Wm[t], fmaf(m1, Wm[360 + t], fmaf(m2, Wm[720 + t], bm[t])));
    }
}

// Packed 3x3 conv over a strip of 2 output rows x NC cols, all 3 och.
// acc[oc][c] = (row r0, row r0+1) packed. rb = buffer row of the first tap
// pair (taps cover buffer rows rb..rb+3). Per (ich, window col) load the
// two disjoint pairs p0=(rb,rb+1), p1=(rb+2,rb+3); middle pm={p0.y,p1.x}.
// gx may be -4 (halo): window col 0 clamps to col 3, feeding only
// discarded outputs.
template<int NC>
__device__ __forceinline__ void conv_rows_pk(
    const float* __restrict__ buf, const float* __restrict__ fw,
    int rb, int gx, v2f acc[3][NC])
{
    const float b0 = fw[81], b1 = fw[82], b2 = fw[83];
#pragma unroll
    for (int c = 0; c < NC; ++c) {
        v2f i0 = {b0, b0}; v2f i1 = {b1, b1}; v2f i2 = {b2, b2};
        acc[0][c] = i0; acc[1][c] = i1; acc[2][c] = i2;
    }
    const int c0 = (gx < 0) ? 3 : gx + 3;
#pragma unroll
    for (int ich = 0; ich < 3; ++ich) {
        const int base = ich * CHS + rb;
        v2f p0[NC + 2], p1[NC + 2], pm[NC + 2];
#pragma unroll
        for (int k = 0; k < NC + 2; ++k) {
            const int cc = (k == 0) ? c0 : (gx + 3 + k);
            p0[k] = ldpair(&buf[base + cc * CSTR]);
            p1[k] = ldpair(&buf[base + cc * CSTR + 2]);
            v2f m = {p0[k].y, p1[k].x};
            pm[k] = m;
        }
#pragma unroll
        for (int dy = 0; dy < 3; ++dy) {
#pragma unroll
            for (int oc = 0; oc < 3; ++oc) {
                const float w0 = fw[oc * 27 + ich * 9 + dy * 3 + 0];
                const float w1 = fw[oc * 27 + ich * 9 + dy * 3 + 1];
                const float w2 = fw[oc * 27 + ich * 9 + dy * 3 + 2];
                v2f W0 = {w0, w0}; v2f W1 = {w1, w1}; v2f W2 = {w2, w2};
#pragma unroll
                for (int c = 0; c < NC; ++c) {
                    const v2f wa = (dy == 0) ? p0[c]     : (dy == 1) ? pm[c]     : p1[c];
                    const v2f wb = (dy == 0) ? p0[c + 1] : (dy == 1) ? pm[c + 1] : p1[c + 1];
                    const v2f wc = (dy == 0) ? p0[c + 2] : (dy == 1) ? pm[c + 2] : p1[c + 2];
                    acc[oc][c] = FMA2(wa, W0, FMA2(wb, W1, FMA2(wc, W2, acc[oc][c])));
                }
            }
        }
    }
}

__global__ __launch_bounds__(512, 4) void conv_att_kernel(
    const float* __restrict__ x, const float* __restrict__ thumb,
    const float* __restrict__ feat, float* __restrict__ out)
{
    __shared__ float buf[BUFSZ];

    int id = blockIdx.x;
    const float* src; float* dst; int H, W, b, trow, tcol;
    if (id < 1024) {                 // big: 8 batches x (16 bands x 8 cols)
        b = id >> 7; const int t = id & 127;
        H = 512; W = 512; trow = (t >> 3) * 32; tcol = (t & 7) * 64;
        src = x; dst = out;
    } else {                         // thumb: 8 batches x 2 bands of 32 rows
        const int i2 = id - 1024;
        b = i2 >> 1; trow = (i2 & 1) * 32; tcol = 0;
        H = 64; W = 64; src = thumb;
        dst = out + (size_t)8 * 3 * 512 * 512;
    }
    const float* fb = feat + b * 360;    // uniform -> scalar loads
    const int tid = threadIdx.x;

    // ---- stage0: issue ALL global loads first (regs), then write LDS ----
    // main: 3ch x 38 rows x 16 interior quads = 1824 units; 3 full rounds
    // of 512 + partial round (tid<288).
    const float* sbg = src + (size_t)b * 3 * H * W;
    float4 stv[3];
#pragma unroll
    for (int i = 0; i < 3; ++i) {
        const int q = tid + 512 * i;           // < 1536
        const int c = q / 608;                 // 608 = 38*16
        const int rem = q - c * 608;
        const int mr = rem >> 4;
        const int k  = rem & 15;
        const int gr = trow + mr - 3;
        const int gc0 = tcol + 4 * k;          // always in [0, W-4]
        float4 v = make_float4(0.f, 0.f, 0.f, 0.f);
        if ((unsigned)gr < (unsigned)H)
            v = *(const float4*)&sbg[(size_t)c * H * W + (size_t)gr * W + gc0];
        stv[i] = v;
    }
    const bool has4 = tid < 288;               // q = 1536..1823 (c = 2)
    float4 st4 = make_float4(0.f, 0.f, 0.f, 0.f);
    if (has4) {
        const int rem = tid + 1536 - 1216;     // c = 2
        const int mr = rem >> 4;
        const int k  = rem & 15;
        const int gr = trow + mr - 3;
        const int gc0 = tcol + 4 * k;
        if ((unsigned)gr < (unsigned)H)
            st4 = *(const float4*)&sbg[(size_t)2 * H * W + (size_t)gr * W + gc0];
    }
    // halo: cols 0..3 (img tcol-4) and 68..71 (img tcol+64), 228 units
    const bool hasH = tid < 228;
    float4 hv = make_float4(0.f, 0.f, 0.f, 0.f);
    int hc = 0, hmr = 0, hside = 0;
    if (hasH) {
        hc = tid / 76;                         // 76 = 38*2
        const int rem = tid - hc * 76;
        hmr = rem >> 1;
        hside = rem & 1;
        const int gr = trow + hmr - 3;
        const int gc0 = tcol + (hside ? 64 : -4);
        const bool rok = (unsigned)gr < (unsigned)H;
        const float* gp = sbg + (size_t)hc * H * W + (size_t)(rok ? gr : 0) * W;
        if (rok && (unsigned)gc0 <= (unsigned)(W - 4)) {
            hv = *(const float4*)&gp[gc0];
        } else {
            hv.x = (rok && (unsigned)(gc0 + 0) < (unsigned)W) ? gp[gc0 + 0] : 0.f;
            hv.y = (rok && (unsigned)(gc0 + 1) < (unsigned)W) ? gp[gc0 + 1] : 0.f;
            hv.z = (rok && (unsigned)(gc0 + 2) < (unsigned)W) ? gp[gc0 + 2] : 0.f;
            hv.w = (rok && (unsigned)(gc0 + 3) < (unsigned)W) ? gp[gc0 + 3] : 0.f;
        }
    }
    // writes (transpose into col-major buffer; row = img + 3)
#pragma unroll
    for (int i = 0; i < 3; ++i) {
        const int q = tid + 512 * i;
        const int c = q / 608;
        const int rem = q - c * 608;
        const int mr = rem >> 4;
        const int k  = rem & 15;
        float* bp = &buf[c * CHS + (4 * k + 4) * CSTR + mr];
        bp[0] = stv[i].x; bp[CSTR] = stv[i].y;
        bp[2 * CSTR] = stv[i].z; bp[3 * CSTR] = stv[i].w;
    }
    if (has4) {
        const int rem = tid + 1536 - 1216;
        const int mr = rem >> 4;
        const int k  = rem & 15;
        float* bp = &buf[2 * CHS + (4 * k + 4) * CSTR + mr];
        bp[0] = st4.x; bp[CSTR] = st4.y; bp[2 * CSTR] = st4.z; bp[3 * CSTR] = st4.w;
    }
    if (hasH) {
        float* bp = &buf[hc * CHS + (hside ? 68 : 0) * CSTR + hmr];
        bp[0] = hv.x; bp[CSTR] = hv.y; bp[2 * CSTR] = hv.z; bp[3 * CSTR] = hv.w;
    }
    // zero pad col 72 (rows 0..37): only gx=64 edge windows read it,
    // feeding discarded outputs — keep values defined.
    if (tid < 114) {
        const int c = tid / 38, r = tid - c * 38;
        buf[c * CHS + 72 * CSTR + r] = 0.f;
    }
    __syncthreads();

    // ---- conv1 reads + residual stash (in-place: all reads before writes)
    // conv1: 18 strips (r0 = 2s-2, img rows -2..33) x 18 quads = 324 units.
    // main 288 (s=tid>>4, gx=4*(tid&15)); halo 36 on lanes 288..323.
    const bool act1 = tid < 324;
    int s1, gx1;
    if (tid < 288) { s1 = tid >> 4; gx1 = 4 * (tid & 15); }
    else { const int v = tid - 288; s1 = v >> 1; gx1 = (v & 1) ? 64 : -4; }
    v2f acc[3][4];
    if (act1) conv_rows_pk<4>(buf, fb, 2 * s1, gx1, acc);   // rb = r0+2 = 2s

    // epilogue mapping (all 512): strip s3e rows (2s3e, 2s3e+1), 2 cols
    const int s3e = tid >> 5;            // 0..15
    const int gx3e = 2 * (tid & 31);     // 0..62
    v2f res2[3][2];
#pragma unroll
    for (int ch = 0; ch < 3; ++ch)
#pragma unroll
        for (int c = 0; c < 2; ++c)
            res2[ch][c] = ldpair(&buf[ch * CHS + (gx3e + 4 + c) * CSTR + (2 * s3e + 3)]);
    __syncthreads();

    // conv1 writes: buffer rows 2s1+1, 2s1+2 (img r0, r0+1 at img+3)
    if (act1) {
#pragma unroll
        for (int oc = 0; oc < 3; ++oc)
#pragma unroll
            for (int c = 0; c < 4; ++c)
                stpair(&buf[oc * CHS + (gx1 + 4 + c) * CSTR + (2 * s1 + 1)],
                       leaky2(acc[oc][c]));
    }
    __syncthreads();

    // ---- conv2: 17 strips (r0 = 2s-1, img rows -1..32) x 18 = 306 units
    const bool act2 = tid < 306;
    int s2, gx2;
    if (tid < 272) { s2 = tid >> 4; gx2 = 4 * (tid & 15); }
    else { const int v = tid - 272; s2 = v >> 1; gx2 = (v & 1) ? 64 : -4; }
    if (act2) conv_rows_pk<4>(buf, fb + 84, 2 * s2 + 1, gx2, acc); // rb = r0+2
    __syncthreads();

    if (act2) {
#pragma unroll
        for (int oc = 0; oc < 3; ++oc)
#pragma unroll
            for (int c = 0; c < 4; ++c)
                stpair(&buf[oc * CHS + (gx2 + 4 + c) * CSTR + (2 * s2 + 2)],
                       leaky2(acc[oc][c]));
    }
    __syncthreads();

    // ---- conv3 (2-col units, ALL 512 threads) + 1x1 chain + attention ----
    {
        v2f y[3][2];
        {
            v2f acc3[3][2];
            conv_rows_pk<2>(buf, fb + 168, 2 * s3e + 2, gx3e, acc3); // rb = r0+2
#pragma unroll
            for (int oc = 0; oc < 3; ++oc)
#pragma unroll
                for (int c = 0; c < 2; ++c) y[oc][c] = leaky2(acc3[oc][c]);
        }

        // 5x conv1x1 chain, packed over the row pair
#pragma unroll
        for (int lay = 0; lay < 5; ++lay) {
            const float* fw = fb + 252 + lay * 12;
            v2f W0 = {fw[0], fw[0]}; v2f W1 = {fw[1], fw[1]}; v2f W2 = {fw[2], fw[2]};
            v2f W3 = {fw[3], fw[3]}; v2f W4 = {fw[4], fw[4]}; v2f W5 = {fw[5], fw[5]};
            v2f W6 = {fw[6], fw[6]}; v2f W7 = {fw[7], fw[7]}; v2f W8 = {fw[8], fw[8]};
            v2f C0 = {fw[9], fw[9]}; v2f C1 = {fw[10], fw[10]}; v2f C2 = {fw[11], fw[11]};
            v2f z0[2], z1[2], z2[2];
#pragma unroll
            for (int c = 0; c < 2; ++c) {
                z0[c] = FMA2(y[0][c], W0, FMA2(y[1][c], W1, FMA2(y[2][c], W2, C0)));
                z1[c] = FMA2(y[0][c], W3, FMA2(y[1][c], W4, FMA2(y[2][c], W5, C1)));
                z2[c] = FMA2(y[0][c], W6, FMA2(y[1][c], W7, FMA2(y[2][c], W8, C2)));
            }
#pragma unroll
            for (int c = 0; c < 2; ++c) {
                y[0][c] = leaky2(z0[c]);
                y[1][c] = leaky2(z1[c]);
                y[2][c] = leaky2(z2[c]);
            }
        }

        // residual + attention + store (2 rows x 2 cols x 3 ch)
        const float invH = 1.f / (float)H;
        const float invW = 1.f / (float)W;
        const int gr0 = trow + 2 * s3e;
        v2f h2 = {(float)gr0 * invH, (float)(gr0 + 1) * invH};
        const float wb = (float)(tcol + gx3e) * invW;
        const v2f one = {1.f, 1.f};
#pragma unroll
        for (int ch = 0; ch < 3; ++ch) {
            const float* fp = fb + 312 + ch * 16;
            v2f PA0 = {fp[0], fp[0]},  PB0 = {fp[1], fp[1]},  PC0 = {fp[2], fp[2]},  PD0 = {fp[3], fp[3]};
            v2f PA1 = {fp[4], fp[4]},  PB1 = {fp[5], fp[5]},  PC1 = {fp[6], fp[6]},  PD1 = {fp[7], fp[7]};
            v2f PA2 = {fp[8], fp[8]},  PB2 = {fp[9], fp[9]},  PC2 = {fp[10], fp[10]}, PD2 = {fp[11], fp[11]};
            v2f PA3 = {fp[12], fp[12]}, PB3 = {fp[13], fp[13]}, PC3 = {fp[14], fp[14]}, PD3 = {fp[15], fp[15]};
            v2f t0 = FMA2(PA0, h2, PD0);
            v2f t1 = FMA2(PA1, h2, PD1);
            v2f t2 = FMA2(PA2, h2, PD2);
            v2f t3 = FMA2(PA3, h2, PD3);
            v2f o[2];
#pragma unroll
            for (int c = 0; c < 2; ++c) {
                const float wcs = wb + (float)c * invW;
                v2f Wc = {wcs, wcs};
                v2f v = y[ch][c] + res2[ch][c];
                v2f a = FMA2(PB0, Wc, FMA2(PC0, v, t0));
                a = a * FMA2(PB1, Wc, FMA2(PC1, v, t1));
                a = a * FMA2(PB2, Wc, FMA2(PC2, v, t2));
                a = a * FMA2(PB3, Wc, FMA2(PC3, v, t3));
                o[c] = v * (one + a);
            }
            v2f ra = {o[0].x, o[1].x};
            v2f rb2 = {o[0].y, o[1].y};
            float* dp = &dst[((size_t)(b * 3 + ch) * H + gr0) * W + tcol + gx3e];
            __builtin_memcpy(dp, &ra, 8);
            __builtin_memcpy(dp + W, &rb2, 8);
        }
    }
}

extern "C" void kernel_launch(void* const* d_in, const int* in_sizes, int n_in,
                              void* d_out, int out_size, void* d_ws, size_t ws_size,
                              hipStream_t stream) {
    const float* x = (const float*)d_in[0];       // (8,3,512,512)
    const float* thumb = (const float*)d_in[1];   // (8,3,64,64)
    const float* Wm = (const float*)d_in[2];      // (3,360)
    const float* bm = (const float*)d_in[3];      // (360,)
    float* out = (float*)d_out;
    float* feat = (float*)d_ws;                   // (8,360)

    prep_kernel<<<8, 384, 0, stream>>>(thumb, Wm, bm, feat);
    // 1024 big-image blocks + 16 thumb blocks
    conv_att_kernel<<<1040, 512, 0, stream>>>(x, thumb, feat, out);
}

// Round 11
// 106.961 us; speedup vs baseline: 1.0562x; 1.0562x over previous
//
#include <hip/hip_runtime.h>

// ---------------------------------------------------------------------------
// Per-batch dynamic conv stack + polynomial attention (f32).
//   feature (8,360) = mean(thumb,(2,3)) @ Wm + bm
//   conv_stack: residual + [3x conv3x3(SAME,leaky 0.2)] -> [5x conv1x1(leaky)]
//   attention:  out = y * (1 + prod_i(a*h + b*w + c*y + d)) per channel
// Outputs: x_out (8,3,512,512) then thumb_out (8,3,64,64), flat f32.
//
// R18 = R16 math/mapping (pk-f32, dy-overlap loads, 4-wave epilogue, T14
// stage0, 16x64 tiles, 256 thr) but SINGLE IN-PLACE buffer (R13 discipline):
//   * R17 lesson: 512-thr/32-row tile regressed ~6us (8-wave barriers,
//     longer phase chain, 1040 blocks). Reverted. But it changed 3 vars;
//     "residency helps" is untested at fixed block shape.
//   * This round: drop the ping-pong B buffer -> LDS 38.6 -> 20.2KB ->
//     residency ceiling 4 -> 7 blocks/CU (16 -> 28 waves) at the SAME
//     256-thr block. Cost: +2 barriers (read/write split per conv layer,
//     acc in regs across the barrier) ~= 1.4us by R13 vs R15.
//   * Single-variable occupancy test. Pre-committed: occupancy flat ->
//     theory dead, revert to R16 and accept ~38us floor.
//   * Buffer row = img row + 3 throughout (rows -3..18, CSTR=23 col-major).
// ---------------------------------------------------------------------------

typedef float v2f __attribute__((ext_vector_type(2)));
#define FMA2(a, b, c) __builtin_elementwise_fma((a), (b), (c))

__device__ __forceinline__ v2f leaky2(v2f v) {
    return __builtin_elementwise_max(v, v * 0.2f);
}

// align-4 LDS pair load/store: compiles to ds_read2_b32 / ds_write2_b32
__device__ __forceinline__ v2f ldpair(const float* p) {
    v2f r; __builtin_memcpy(&r, p, 8); return r;
}
__device__ __forceinline__ void stpair(float* p, v2f v) {
    __builtin_memcpy(p, &v, 8);
}

constexpr int NCOLS = 73;           // cols -4..67 + zero pad col 72
constexpr int CSTR  = 23;           // 22 rows + 1 pad; 4*23=92=28 mod 32 banks
constexpr int CHS   = NCOLS * CSTR; // 1679
constexpr int BUFSZ = 3 * CHS + 4;  // 20.2KB

__global__ __launch_bounds__(384) void prep_kernel(
    const float* __restrict__ thumb, const float* __restrict__ Wm,
    const float* __restrict__ bm, float* __restrict__ feat)
{
    const int b = blockIdx.x;                // 8 blocks
    const int t = threadIdx.x;               // 384
    const int ch = t >> 7;                   // 0..2
    const int l  = t & 127;
    const float4* p = (const float4*)(thumb + (size_t)b * 3 * 4096);
    float s = 0.f;
#pragma unroll
    for (int k = 0; k < 8; ++k) {
        float4 v = p[ch * 1024 + l + k * 128];
        s += v.x + v.y + v.z + v.w;
    }
    __shared__ float red[384];
    red[t] = s;
    __syncthreads();
    for (int off = 64; off > 0; off >>= 1) {
        if (l < off) red[t] += red[t + off];
        __syncthreads();
    }
    if (t < 360) {
        const float sc = 1.f / 4096.f;
        const float m0 = red[0] * sc, m1 = red[128] * sc, m2 = red[256] * sc;
        feat[b * 360 + t] =
            fmaf(m0, Wm[t], fmaf(m1, Wm[360 + t], fmaf(m2, Wm[720 + t], bm[t])));
    }
}

// Packed 3x3 conv over a strip of 2 output rows x NC cols, all 3 och.
// acc[oc][c] = (row r0, row r0+1) packed. rb = buffer row of the first tap
// pair (taps cover buffer rows rb..rb+3). Per (ich, window col) load the
// two disjoint pairs p0=(rb,rb+1), p1=(rb+2,rb+3); middle pm={p0.y,p1.x}.
// gx may be -4 (halo): window col 0 clamps to col 3, feeding only
// discarded outputs.
template<int NC>
__device__ __forceinline__ void conv_rows_pk(
    const float* __restrict__ buf, const float* __restrict__ fw,
    int rb, int gx, v2f acc[3][NC])
{
    const float b0 = fw[81], b1 = fw[82], b2 = fw[83];
#pragma unroll
    for (int c = 0; c < NC; ++c) {
        v2f i0 = {b0, b0}; v2f i1 = {b1, b1}; v2f i2 = {b2, b2};
        acc[0][c] = i0; acc[1][c] = i1; acc[2][c] = i2;
    }
    const int c0 = (gx < 0) ? 3 : gx + 3;
#pragma unroll
    for (int ich = 0; ich < 3; ++ich) {
        const int base = ich * CHS + rb;
        v2f p0[NC + 2], p1[NC + 2], pm[NC + 2];
#pragma unroll
        for (int k = 0; k < NC + 2; ++k) {
            const int cc = (k == 0) ? c0 : (gx + 3 + k);
            p0[k] = ldpair(&buf[base + cc * CSTR]);
            p1[k] = ldpair(&buf[base + cc * CSTR + 2]);
            v2f m = {p0[k].y, p1[k].x};
            pm[k] = m;
        }
#pragma unroll
        for (int dy = 0; dy < 3; ++dy) {
#pragma unroll
            for (int oc = 0; oc < 3; ++oc) {
                const float w0 = fw[oc * 27 + ich * 9 + dy * 3 + 0];
                const float w1 = fw[oc * 27 + ich * 9 + dy * 3 + 1];
                const float w2 = fw[oc * 27 + ich * 9 + dy * 3 + 2];
                v2f W0 = {w0, w0}; v2f W1 = {w1, w1}; v2f W2 = {w2, w2};
#pragma unroll
                for (int c = 0; c < NC; ++c) {
                    const v2f wa = (dy == 0) ? p0[c]     : (dy == 1) ? pm[c]     : p1[c];
                    const v2f wb = (dy == 0) ? p0[c + 1] : (dy == 1) ? pm[c + 1] : p1[c + 1];
                    const v2f wc = (dy == 0) ? p0[c + 2] : (dy == 1) ? pm[c + 2] : p1[c + 2];
                    acc[oc][c] = FMA2(wa, W0, FMA2(wb, W1, FMA2(wc, W2, acc[oc][c])));
                }
            }
        }
    }
}

__global__ __launch_bounds__(256, 4) void conv_att_kernel(
    const float* __restrict__ x, const float* __restrict__ thumb,
    const float* __restrict__ feat, float* __restrict__ out)
{
    __shared__ float buf[BUFSZ];

    int id = blockIdx.x;
    const float* src; float* dst; int H, W, b, trow, tcol;
    if (id < 2048) {                 // big: 8 batches x (32 row x 8 col) tiles
        b = id >> 8; const int t = id & 255;
        H = 512; W = 512; trow = (t >> 3) * 16; tcol = (t & 7) * 64;
        src = x; dst = out;
    } else {                         // thumb: 8 batches x 4 row tiles
        const int i2 = id - 2048;
        b = i2 >> 2; trow = (i2 & 3) * 16; tcol = 0;
        H = 64; W = 64; src = thumb;
        dst = out + (size_t)8 * 3 * 512 * 512;
    }
    const float* fb = feat + b * 360;    // uniform -> scalar loads
    const int tid = threadIdx.x;

    // ---- stage0: issue ALL global loads first (regs), then write LDS ----
    const float* sbg = src + (size_t)b * 3 * H * W;
    float4 stv[4];
#pragma unroll
    for (int i = 0; i < 4; ++i) {
        const int q = tid + 256 * i;           // < 1024
        const int c = q / 352;                 // 352 = 22*16
        const int rem = q - c * 352;
        const int mr = rem >> 4;
        const int k  = rem & 15;
        const int gr = trow + mr - 3;
        const int gc0 = tcol + 4 * k;          // always in [0, W-4]
        float4 v = make_float4(0.f, 0.f, 0.f, 0.f);
        if ((unsigned)gr < (unsigned)H)
            v = *(const float4*)&sbg[(size_t)c * H * W + (size_t)gr * W + gc0];
        stv[i] = v;
    }
    const bool has5 = tid < 32;                // q = 1024..1055 (c=2)
    float4 st5 = make_float4(0.f, 0.f, 0.f, 0.f);
    if (has5) {
        const int rem = tid + 1024 - 704;      // c = 2
        const int mr = rem >> 4;
        const int k  = rem & 15;
        const int gr = trow + mr - 3;
        const int gc0 = tcol + 4 * k;
        if ((unsigned)gr < (unsigned)H)
            st5 = *(const float4*)&sbg[(size_t)2 * H * W + (size_t)gr * W + gc0];
    }
    // halo: cols 0..3 (img tcol-4) and 68..71 (img tcol+64), 132 units
    const bool hasH = tid < 132;
    float4 hv = make_float4(0.f, 0.f, 0.f, 0.f);
    int hc = 0, hmr = 0, hside = 0;
    if (hasH) {
        hc = tid / 44;                         // 44 = 22*2
        const int rem = tid - hc * 44;
        hmr = rem >> 1;
        hside = rem & 1;
        const int gr = trow + hmr - 3;
        const int gc0 = tcol + (hside ? 64 : -4);
        const bool rok = (unsigned)gr < (unsigned)H;
        const float* gp = sbg + (size_t)hc * H * W + (size_t)(rok ? gr : 0) * W;
        if (rok && (unsigned)gc0 <= (unsigned)(W - 4)) {
            hv = *(const float4*)&gp[gc0];
        } else {
            hv.x = (rok && (unsigned)(gc0 + 0) < (unsigned)W) ? gp[gc0 + 0] : 0.f;
            hv.y = (rok && (unsigned)(gc0 + 1) < (unsigned)W) ? gp[gc0 + 1] : 0.f;
            hv.z = (rok && (unsigned)(gc0 + 2) < (unsigned)W) ? gp[gc0 + 2] : 0.f;
            hv.w = (rok && (unsigned)(gc0 + 3) < (unsigned)W) ? gp[gc0 + 3] : 0.f;
        }
    }
    // writes (transpose into col-major buffer; row = img + 3)
#pragma unroll
    for (int i = 0; i < 4; ++i) {
        const int q = tid + 256 * i;
        const int c = q / 352;
        const int rem = q - c * 352;
        const int mr = rem >> 4;
        const int k  = rem & 15;
        float* bp = &buf[c * CHS + (4 * k + 4) * CSTR + mr];
        bp[0] = stv[i].x; bp[CSTR] = stv[i].y;
        bp[2 * CSTR] = stv[i].z; bp[3 * CSTR] = stv[i].w;
    }
    if (has5) {
        const int rem = tid + 1024 - 704;
        const int mr = rem >> 4;
        const int k  = rem & 15;
        float* bp = &buf[2 * CHS + (4 * k + 4) * CSTR + mr];
        bp[0] = st5.x; bp[CSTR] = st5.y; bp[2 * CSTR] = st5.z; bp[3 * CSTR] = st5.w;
    }
    if (hasH) {
        float* bp = &buf[hc * CHS + (hside ? 68 : 0) * CSTR + hmr];
        bp[0] = hv.x; bp[CSTR] = hv.y; bp[2 * CSTR] = hv.z; bp[3 * CSTR] = hv.w;
    }
    // zero pad col 72 (rows 0..21): only gx=64 edge windows read it,
    // feeding discarded outputs — keep values defined.
    if (tid < 66) {
        const int c = tid / 22, mr = tid - c * 22;
        buf[c * CHS + 72 * CSTR + mr] = 0.f;
    }
    __syncthreads();

    // ---- phase 2: conv1 reads + residual stash (all reads before writes)
    // conv1: 10 strips (r0 = 2s-2) x 18 quads = 180 units; main 160, halo 20.
    const bool act1 = tid < 180;
    int s1, gx1;
    if (tid < 160) { s1 = tid >> 4; gx1 = 4 * (tid & 15); }
    else { const int v = tid - 160; s1 = v >> 1; gx1 = (v & 1) ? 64 : -4; }
    v2f acc[3][4];
    if (act1) conv_rows_pk<4>(buf, fb, 2 * s1, gx1, acc);   // rb = r0+2 = 2s

    // epilogue mapping (all 256): strip s3e rows (2s3e, 2s3e+1), 2 cols
    const int s3e = tid >> 5;            // 0..7
    const int gx3e = 2 * (tid & 31);     // 0..62
    v2f res2[3][2];
#pragma unroll
    for (int ch = 0; ch < 3; ++ch)
#pragma unroll
        for (int c = 0; c < 2; ++c)
            res2[ch][c] = ldpair(&buf[ch * CHS + (gx3e + 4 + c) * CSTR + (2 * s3e + 3)]);
    __syncthreads();

    // conv1 writes: buffer rows 2s1+1, 2s1+2 (img rows r0, r0+1 at img+3)
    if (act1) {
#pragma unroll
        for (int oc = 0; oc < 3; ++oc)
#pragma unroll
            for (int c = 0; c < 4; ++c)
                stpair(&buf[oc * CHS + (gx1 + 4 + c) * CSTR + (2 * s1 + 1)],
                       leaky2(acc[oc][c]));
    }
    __syncthreads();

    // ---- phase 3: conv2 (in-place): 9 strips (r0 = 2s-1) x 18 = 162 units
    const bool act2 = tid < 162;
    int s2, gx2;
    if (tid < 144) { s2 = tid >> 4; gx2 = 4 * (tid & 15); }
    else { const int v = tid - 144; s2 = v >> 1; gx2 = (v & 1) ? 64 : -4; }
    if (act2) conv_rows_pk<4>(buf, fb + 84, 2 * s2 + 1, gx2, acc); // rb = r0+2
    __syncthreads();

    // conv2 writes: buffer rows 2s2+2, 2s2+3 (img rows r0, r0+1 at img+3)
    if (act2) {
#pragma unroll
        for (int oc = 0; oc < 3; ++oc)
#pragma unroll
            for (int c = 0; c < 4; ++c)
                stpair(&buf[oc * CHS + (gx2 + 4 + c) * CSTR + (2 * s2 + 2)],
                       leaky2(acc[oc][c]));
    }
    __syncthreads();

    // ---- phase 4: conv3 (2-col units, ALL 256 threads) + 1x1 chain
    //      + residual + attention + 8B stores ----
    {
        v2f y[3][2];
        {
            v2f acc3[3][2];
            conv_rows_pk<2>(buf, fb + 168, 2 * s3e + 2, gx3e, acc3); // rb = r0+2
#pragma unroll
            for (int oc = 0; oc < 3; ++oc)
#pragma unroll
                for (int c = 0; c < 2; ++c) y[oc][c] = leaky2(acc3[oc][c]);
        }

        // 5x conv1x1 chain, packed over the row pair
#pragma unroll
        for (int lay = 0; lay < 5; ++lay) {
            const float* fw = fb + 252 + lay * 12;
            v2f W0 = {fw[0], fw[0]}; v2f W1 = {fw[1], fw[1]}; v2f W2 = {fw[2], fw[2]};
            v2f W3 = {fw[3], fw[3]}; v2f W4 = {fw[4], fw[4]}; v2f W5 = {fw[5], fw[5]};
            v2f W6 = {fw[6], fw[6]}; v2f W7 = {fw[7], fw[7]}; v2f W8 = {fw[8], fw[8]};
            v2f C0 = {fw[9], fw[9]}; v2f C1 = {fw[10], fw[10]}; v2f C2 = {fw[11], fw[11]};
            v2f z0[2], z1[2], z2[2];
#pragma unroll
            for (int c = 0; c < 2; ++c) {
                z0[c] = FMA2(y[0][c], W0, FMA2(y[1][c], W1, FMA2(y[2][c], W2, C0)));
                z1[c] = FMA2(y[0][c], W3, FMA2(y[1][c], W4, FMA2(y[2][c], W5, C1)));
                z2[c] = FMA2(y[0][c], W6, FMA2(y[1][c], W7, FMA2(y[2][c], W8, C2)));
            }
#pragma unroll
            for (int c = 0; c < 2; ++c) {
                y[0][c] = leaky2(z0[c]);
                y[1][c] = leaky2(z1[c]);
                y[2][c] = leaky2(z2[c]);
            }
        }

        // residual + attention + store (2 rows x 2 cols x 3 ch)
        const float invH = 1.f / (float)H;
        const float invW = 1.f / (float)W;
        const int gr0 = trow + 2 * s3e;
        v2f h2 = {(float)gr0 * invH, (float)(gr0 + 1) * invH};
        const float wb = (float)(tcol + gx3e) * invW;
        const v2f one = {1.f, 1.f};
#pragma unroll
        for (int ch = 0; ch < 3; ++ch) {
            const float* fp = fb + 312 + ch * 16;
            v2f PA0 = {fp[0], fp[0]},  PB0 = {fp[1], fp[1]},  PC0 = {fp[2], fp[2]},  PD0 = {fp[3], fp[3]};
            v2f PA1 = {fp[4], fp[4]},  PB1 = {fp[5], fp[5]},  PC1 = {fp[6], fp[6]},  PD1 = {fp[7], fp[7]};
            v2f PA2 = {fp[8], fp[8]},  PB2 = {fp[9], fp[9]},  PC2 = {fp[10], fp[10]}, PD2 = {fp[11], fp[11]};
            v2f PA3 = {fp[12], fp[12]}, PB3 = {fp[13], fp[13]}, PC3 = {fp[14], fp[14]}, PD3 = {fp[15], fp[15]};
            v2f t0 = FMA2(PA0, h2, PD0);
            v2f t1 = FMA2(PA1, h2, PD1);
            v2f t2 = FMA2(PA2, h2, PD2);
            v2f t3 = FMA2(PA3, h2, PD3);
            v2f o[2];
#pragma unroll
            for (int c = 0; c < 2; ++c) {
                const float wcs = wb + (float)c * invW;
                v2f Wc = {wcs, wcs};
                v2f v = y[ch][c] + res2[ch][c];
                v2f a = FMA2(PB0, Wc, FMA2(PC0, v, t0));
                a = a * FMA2(PB1, Wc, FMA2(PC1, v, t1));
                a = a * FMA2(PB2, Wc, FMA2(PC2, v, t2));
                a = a * FMA2(PB3, Wc, FMA2(PC3, v, t3));
                o[c] = v * (one + a);
            }
            v2f ra = {o[0].x, o[1].x};
            v2f rb2 = {o[0].y, o[1].y};
            float* dp = &dst[((size_t)(b * 3 + ch) * H + gr0) * W + tcol + gx3e];
            __builtin_memcpy(dp, &ra, 8);
            __builtin_memcpy(dp + W, &rb2, 8);
        }
    }
}

extern "C" void kernel_launch(void* const* d_in, const int* in_sizes, int n_in,
                              void* d_out, int out_size, void* d_ws, size_t ws_size,
                              hipStream_t stream) {
    const float* x = (const float*)d_in[0];       // (8,3,512,512)
    const float* thumb = (const float*)d_in[1];   // (8,3,64,64)
    const float* Wm = (const float*)d_in[2];      // (3,360)
    const float* bm = (const float*)d_in[3];      // (360,)
    float* out = (float*)d_out;
    float* feat = (float*)d_ws;                   // (8,360)

    prep_kernel<<<8, 384, 0, stream>>>(thumb, Wm, bm, feat);
    // 2048 big-image blocks + 32 thumb blocks
    conv_att_kernel<<<2080, 256, 0, stream>>>(x, thumb, feat, out);
}